// Round 3
// baseline (506.074 us; speedup 1.0000x reference)
//
#include <hip/hip_runtime.h>

#define NN 50000
#define EE 600000
#define ET 650000  // EE + NN self loops
#define NGRAPH 64
#define NCLASS 10
#define NEG 0.2f

typedef unsigned short u16;
typedef __attribute__((ext_vector_type(8))) short short8;
typedef __attribute__((ext_vector_type(4))) float f32x4;

__device__ __forceinline__ float bf2f(u16 u) {
  union { float f; unsigned int i; } v; v.i = ((unsigned int)u) << 16; return v.f;
}
__device__ __forceinline__ u16 f2bf(float f) {
  union { float f; unsigned int i; } v; v.f = f;
  unsigned int r = v.i + 0x7FFFu + ((v.i >> 16) & 1u);
  return (u16)(r >> 16);
}
__device__ __forceinline__ float lrelu(float x) { return x >= 0.f ? x : NEG * x; }

// ---------------- dtype probe: are float arrays stored as f32 or bf16? ----------------
__global__ __launch_bounds__(256) void detect_k(const void* __restrict__ x, int* __restrict__ flag) {
  __shared__ int sc[256];
  const float* xf = (const float*)x;
  int t = threadIdx.x, c = 0;
  for (int i = 0; i < 4; ++i) {
    float a = fabsf(xf[t * 4 + i]);
    if (a > 1e-4f && a < 100.f) c++;  // NaN compares false
  }
  sc[t] = c;
  __syncthreads();
  for (int o = 128; o > 0; o >>= 1) { if (t < o) sc[t] += sc[t + o]; __syncthreads(); }
  if (t == 0) flag[0] = (sc[0] >= 512) ? 1 : 0;  // 1 = inputs are f32
}

// canonicalize x -> bf16
__global__ __launch_bounds__(256) void conv_x_k(const void* __restrict__ x, u16* __restrict__ xc,
                                                const int* __restrict__ flag) {
  int i = (blockIdx.x * 256 + threadIdx.x) * 4;
  if (i >= NN * 128) return;
  if (flag[0]) {
    const float* s = (const float*)x + i;
    xc[i] = f2bf(s[0]); xc[i + 1] = f2bf(s[1]); xc[i + 2] = f2bf(s[2]); xc[i + 3] = f2bf(s[3]);
  } else {
    *(uint2*)(xc + i) = *(const uint2*)((const u16*)x + i);
  }
}

// canonicalize W0..2 -> bf16 (3 x 16384)
__global__ __launch_bounds__(256) void conv_w_k(const void* __restrict__ w0, const void* __restrict__ w1,
                                                const void* __restrict__ w2, u16* __restrict__ wc,
                                                const int* __restrict__ flag) {
  int idx = blockIdx.x * 256 + threadIdx.x;
  const void* s = (idx >> 14) == 0 ? w0 : ((idx >> 14) == 1 ? w1 : w2);
  int l = idx & 16383;
  wc[idx] = flag[0] ? f2bf(((const float*)s)[l]) : ((const u16*)s)[l];
}

// canonicalize small params -> f32 block
// pf layout: l*384 + {a_src:0, a_dst:128, b:256}; lin_w at 1152 (1280); lin_b at 2432 (10)
__global__ __launch_bounds__(256) void conv_p_k(const void* as0, const void* ad0, const void* b0,
                                                const void* as1, const void* ad1, const void* b1,
                                                const void* as2, const void* ad2, const void* b2,
                                                const void* lw, const void* lb,
                                                float* __restrict__ pf, const int* __restrict__ flag) {
  const void* srcs[11] = {as0, ad0, b0, as1, ad1, b1, as2, ad2, b2, lw, lb};
  const int offs[12] = {0, 128, 256, 384, 512, 640, 768, 896, 1024, 1152, 2432, 2442};
  int f = flag[0];
  for (int idx = threadIdx.x; idx < 2442; idx += 256) {
    int k = 0;
    while (idx >= offs[k + 1]) k++;
    int l = idx - offs[k];
    pf[idx] = f ? ((const float*)srcs[k])[l] : bf2f(((const u16*)srcs[k])[l]);
  }
}

// ---------------- CSR build ----------------
__global__ __launch_bounds__(256) void init_k(int* counts, int* fill, int* roff, float* psum) {
  int i = blockIdx.x * 256 + threadIdx.x;
  if (i < NN) { counts[i] = 1; fill[i] = 0; }  // 1 = self loop
  if (i < NGRAPH * 128) psum[i] = 0.f;
  if (i == 0) roff[NN] = ET;
}

__global__ __launch_bounds__(256) void count_k(const int* __restrict__ ei, int* __restrict__ counts) {
  int e = blockIdx.x * 256 + threadIdx.x;
  if (e < EE) atomicAdd(&counts[ei[EE + e]], 1);
}

__global__ __launch_bounds__(256) void scan_a(const int* __restrict__ counts, int* __restrict__ part) {
  __shared__ int s[256];
  int t = threadIdx.x, i = blockIdx.x * 256 + t;
  s[t] = (i < NN) ? counts[i] : 0;
  __syncthreads();
  for (int o = 128; o > 0; o >>= 1) { if (t < o) s[t] += s[t + o]; __syncthreads(); }
  if (t == 0) part[blockIdx.x] = s[0];
}

__global__ __launch_bounds__(256) void scan_b(int* part) {  // 196 partials
  __shared__ int s[256];
  int t = threadIdx.x;
  int v = (t < 196) ? part[t] : 0;
  s[t] = v;
  __syncthreads();
  for (int o = 1; o < 256; o <<= 1) {
    int add = (t >= o) ? s[t - o] : 0;
    __syncthreads();
    s[t] += add;
    __syncthreads();
  }
  if (t < 196) part[t] = s[t] - v;  // exclusive
}

__global__ __launch_bounds__(256) void scan_c(const int* __restrict__ counts, const int* __restrict__ part,
                                              int* __restrict__ roff) {
  __shared__ int s[256];
  int t = threadIdx.x, i = blockIdx.x * 256 + t;
  int v = (i < NN) ? counts[i] : 0;
  s[t] = v;
  __syncthreads();
  for (int o = 1; o < 256; o <<= 1) {
    int add = (t >= o) ? s[t - o] : 0;
    __syncthreads();
    s[t] += add;
    __syncthreads();
  }
  if (i < NN) roff[i] = part[blockIdx.x] + s[t] - v;
}

__global__ __launch_bounds__(256) void fill_k(const int* __restrict__ ei, const int* __restrict__ roff,
                                              int* __restrict__ fill, int* __restrict__ csr) {
  int i = blockIdx.x * 256 + threadIdx.x;
  if (i >= ET) return;
  int s, d;
  if (i < EE) { s = ei[i]; d = ei[EE + i]; } else { s = d = i - EE; }
  int pos = roff[d] + atomicAdd(&fill[d], 1);
  if ((unsigned)pos < (unsigned)ET) csr[pos] = s;
}

// ---------------- GEMM: h[M,128] = A[M,128](bf16) @ W[128,128](bf16), f32 out ----
__global__ __launch_bounds__(256) void gemm_k(const u16* __restrict__ A, const u16* __restrict__ Wg,
                                              float* __restrict__ H) {
  __shared__ u16 lds[128 * 128];  // W, XOR-swizzled 16B granules
  int tid = threadIdx.x;
  for (int idx = tid; idx < 128 * 128; idx += 256) {
    int k = idx >> 7, c = idx & 127;
    int slot = (k >> 3) ^ (c & 15);
    lds[c * 128 + slot * 8 + (k & 7)] = Wg[idx];
  }
  __syncthreads();
  int wid = tid >> 6, lane = tid & 63;
  int l15 = lane & 15, quad = lane >> 4;
  int row0 = blockIdx.x * 64 + wid * 16;
  f32x4 acc[8];
#pragma unroll
  for (int t = 0; t < 8; ++t) { acc[t][0] = 0.f; acc[t][1] = 0.f; acc[t][2] = 0.f; acc[t][3] = 0.f; }
  int arow = row0 + l15;
  if (arow >= NN) arow = NN - 1;  // clamp: pad-row outputs never stored
#pragma unroll
  for (int ks = 0; ks < 4; ++ks) {
    short8 a = *(const short8*)(A + (size_t)arow * 128 + ks * 32 + quad * 8);
#pragma unroll
    for (int t = 0; t < 8; ++t) {
      int col = t * 16 + l15;
      int slot = (ks * 4 + quad) ^ l15;
      short8 b = *(const short8*)(&lds[col * 128 + slot * 8]);
      acc[t] = __builtin_amdgcn_mfma_f32_16x16x32_bf16(a, b, acc[t], 0, 0, 0);
    }
  }
#pragma unroll
  for (int t = 0; t < 8; ++t) {
#pragma unroll
    for (int r = 0; r < 4; ++r) {
      int row = row0 + quad * 4 + r;
      if (row < NN) H[(size_t)row * 128 + t * 16 + l15] = acc[t][r];
    }
  }
}

// ---------------- per-node attention dots ----------------
__global__ __launch_bounds__(256) void alpha_k(const float* __restrict__ h, const float* __restrict__ a_s,
                                               const float* __restrict__ a_d, float* __restrict__ al_s,
                                               float* __restrict__ al_d) {
  int wid = threadIdx.x >> 6, lane = threadIdx.x & 63;
  int n = blockIdx.x * 4 + wid;
  if (n >= NN) return;
  float h0 = h[(size_t)n * 128 + lane];
  float h1 = h[(size_t)n * 128 + 64 + lane];
  float s0 = h0 * a_s[lane];
  float s1 = h1 * a_s[64 + lane];
  float d0 = h0 * a_d[lane];
  float d1 = h1 * a_d[64 + lane];
  for (int o = 32; o > 0; o >>= 1) {
    s0 += __shfl_xor(s0, o); s1 += __shfl_xor(s1, o);
    d0 += __shfl_xor(d0, o); d1 += __shfl_xor(d1, o);
  }
  if (lane == 0) {
    al_s[2 * n] = s0; al_s[2 * n + 1] = s1;
    al_d[2 * n] = d0; al_d[2 * n + 1] = d1;
  }
}

// ---------------- segment softmax + aggregation (one wave per dst node) ----------------
__global__ __launch_bounds__(256) void agg_k(const float* __restrict__ h, const float* __restrict__ al_s,
                                             const float* __restrict__ al_d, const int* __restrict__ roff,
                                             const int* __restrict__ csr, const float* __restrict__ bias,
                                             u16* __restrict__ oB, float* __restrict__ psum,
                                             const int* __restrict__ batch, int last) {
  int wid = threadIdx.x >> 6, lane = threadIdx.x & 63;
  int n = blockIdx.x * 4 + wid;
  if (n >= NN) return;
  int base = roff[n], deg = roff[n + 1] - base;
  if (deg < 0) deg = 0;
  if (deg > ET) deg = ET;
  if ((unsigned)base >= (unsigned)ET) base = 0;
  float ad0 = al_d[2 * n], ad1 = al_d[2 * n + 1];
  // pass 1: segment max
  float m0 = -1e30f, m1 = -1e30f;
  for (int i = lane; i < deg; i += 64) {
    int idx = base + i; if ((unsigned)idx >= (unsigned)ET) idx = 0;
    int s = csr[idx]; if ((unsigned)s >= (unsigned)NN) s = 0;
    m0 = fmaxf(m0, lrelu(al_s[2 * s] + ad0));
    m1 = fmaxf(m1, lrelu(al_s[2 * s + 1] + ad1));
  }
  for (int o = 32; o > 0; o >>= 1) {
    m0 = fmaxf(m0, __shfl_xor(m0, o));
    m1 = fmaxf(m1, __shfl_xor(m1, o));
  }
  // pass 2: exp weights + weighted message sum
  float acc0 = 0.f, acc1 = 0.f, den0 = 0.f, den1 = 0.f;
  for (int c0 = 0; c0 < deg; c0 += 64) {
    int cnt = min(64, deg - c0);
    int sv = 0; float w0 = 0.f, w1 = 0.f;
    if (lane < cnt) {
      int idx = base + c0 + lane; if ((unsigned)idx >= (unsigned)ET) idx = 0;
      sv = csr[idx]; if ((unsigned)sv >= (unsigned)NN) sv = 0;
      w0 = __expf(lrelu(al_s[2 * sv] + ad0) - m0);
      w1 = __expf(lrelu(al_s[2 * sv + 1] + ad1) - m1);
    }
    for (int j = 0; j < cnt; ++j) {
      int sj = __shfl(sv, j);
      float w0j = __shfl(w0, j);
      float w1j = __shfl(w1, j);
      const float* hp = h + (size_t)sj * 128;
      acc0 += w0j * hp[lane];
      acc1 += w1j * hp[64 + lane];
      den0 += w0j; den1 += w1j;
    }
  }
  float v0 = acc0 / (den0 + 1e-16f) + bias[lane];
  float v1 = acc1 / (den1 + 1e-16f) + bias[64 + lane];
  if (last) {  // fused mean-pool numerator (mean over graph applied in final_k)
    int g = batch[n]; if ((unsigned)g >= (unsigned)NGRAPH) g = 0;
    atomicAdd(&psum[g * 128 + lane], v0);
    atomicAdd(&psum[g * 128 + 64 + lane], v1);
  } else {  // ELU, store bf16 for next layer's MFMA
    v0 = v0 > 0.f ? v0 : __expf(v0) - 1.f;
    v1 = v1 > 0.f ? v1 : __expf(v1) - 1.f;
    oB[(size_t)n * 128 + lane] = f2bf(v0);
    oB[(size_t)n * 128 + 64 + lane] = f2bf(v1);
  }
}

// ---------------- final: mean + linear + softmax (f32 output!) ----------------
__device__ __forceinline__ int lbound(const int* a, int n, int v) {
  int lo = 0, hi = n;
  while (lo < hi) { int mid = (lo + hi) >> 1; if (a[mid] < v) lo = mid + 1; else hi = mid; }
  return lo;
}

__global__ __launch_bounds__(128) void final_k(const float* __restrict__ psum, const int* __restrict__ batch,
                                               const float* __restrict__ lw, const float* __restrict__ lb,
                                               float* __restrict__ out) {
  __shared__ float p[128];
  __shared__ float lg[NCLASS];
  int g = blockIdx.x, t = threadIdx.x;
  int cnt = lbound(batch, NN, g + 1) - lbound(batch, NN, g);
  p[t] = psum[g * 128 + t] / fmaxf((float)cnt, 1.f);
  __syncthreads();
  if (t < NCLASS) {
    float acc = lb[t];
    for (int c = 0; c < 128; ++c) acc += p[c] * lw[c * NCLASS + t];
    lg[t] = acc;
  }
  __syncthreads();
  if (t < NCLASS) {
    float m = -1e30f;
    for (int j = 0; j < NCLASS; ++j) m = fmaxf(m, lg[j]);
    float sum = 0.f;
    for (int j = 0; j < NCLASS; ++j) sum += __expf(lg[j] - m);
    out[g * NCLASS + t] = __expf(lg[t] - m) / sum;  // f32 store — d_out is float32
  }
}

extern "C" void kernel_launch(void* const* d_in, const int* in_sizes, int n_in,
                              void* d_out, int out_size, void* d_ws, size_t ws_size,
                              hipStream_t stream) {
  const void* x = d_in[0];
  const int* ei = (const int*)d_in[1];
  const int* batch = (const int*)d_in[2];
  float* out = (float*)d_out;

  size_t off = 0;
  auto alloc = [&](size_t bytes) -> void* {
    void* p = (char*)d_ws + off;
    off += (bytes + 255) & ~(size_t)255;
    return p;
  };
  int* flag = (int*)alloc(256);
  u16* xc = (u16*)alloc((size_t)NN * 128 * 2);
  u16* wc = (u16*)alloc((size_t)3 * 16384 * 2);
  float* pf = (float*)alloc(2442 * 4);
  float* h = (float*)alloc((size_t)NN * 128 * 4);
  u16* xb = (u16*)alloc((size_t)NN * 128 * 2);
  float* al_s = (float*)alloc((size_t)NN * 2 * 4);
  float* al_d = (float*)alloc((size_t)NN * 2 * 4);
  int* counts = (int*)alloc((size_t)NN * 4);
  int* fillc = (int*)alloc((size_t)NN * 4);
  int* roff = (int*)alloc((size_t)(NN + 1) * 4);
  int* csr = (int*)alloc((size_t)ET * 4);
  int* part = (int*)alloc(256 * 4);
  float* psum = (float*)alloc((size_t)NGRAPH * 128 * 4);
  // total ~55.4 MB

  detect_k<<<1, 256, 0, stream>>>(x, flag);
  conv_x_k<<<6250, 256, 0, stream>>>(x, xc, flag);
  conv_w_k<<<192, 256, 0, stream>>>(d_in[3], d_in[7], d_in[11], wc, flag);
  conv_p_k<<<1, 256, 0, stream>>>(d_in[4], d_in[5], d_in[6], d_in[8], d_in[9], d_in[10],
                                  d_in[12], d_in[13], d_in[14], d_in[15], d_in[16], pf, flag);

  init_k<<<196, 256, 0, stream>>>(counts, fillc, roff, psum);
  count_k<<<2344, 256, 0, stream>>>(ei, counts);
  scan_a<<<196, 256, 0, stream>>>(counts, part);
  scan_b<<<1, 256, 0, stream>>>(part);
  scan_c<<<196, 256, 0, stream>>>(counts, part, roff);
  fill_k<<<2540, 256, 0, stream>>>(ei, roff, fillc, csr);

  const u16* Ain = xc;
  for (int l = 0; l < 3; ++l) {
    gemm_k<<<782, 256, 0, stream>>>(Ain, wc + l * 16384, h);
    alpha_k<<<12500, 256, 0, stream>>>(h, pf + l * 384, pf + l * 384 + 128, al_s, al_d);
    agg_k<<<12500, 256, 0, stream>>>(h, al_s, al_d, roff, csr, pf + l * 384 + 256,
                                     xb, psum, batch, l == 2);
    Ain = xb;
  }
  final_k<<<NGRAPH, 128, 0, stream>>>(psum, batch, pf + 1152, pf + 2432, out);
}

// Round 4
// 402.411 us; speedup vs baseline: 1.2576x; 1.2576x over previous
//
#include <hip/hip_runtime.h>

#define NN 50000
#define EE 600000
#define ET 650000  // EE + NN self loops
#define NGRAPH 64
#define NCLASS 10
#define NEG 0.2f

typedef unsigned short u16;
typedef __attribute__((ext_vector_type(8))) short short8;
typedef __attribute__((ext_vector_type(4))) float f32x4;

__device__ __forceinline__ float bf2f(u16 u) {
  union { float f; unsigned int i; } v; v.i = ((unsigned int)u) << 16; return v.f;
}
__device__ __forceinline__ u16 f2bf(float f) {
  union { float f; unsigned int i; } v; v.f = f;
  unsigned int r = v.i + 0x7FFFu + ((v.i >> 16) & 1u);
  return (u16)(r >> 16);
}
__device__ __forceinline__ float lrelu(float x) { return x >= 0.f ? x : NEG * x; }
// packed bf16x2 helpers: lo half = channel c, hi half = channel c+64
__device__ __forceinline__ float plo(unsigned p) {
  union { float f; unsigned int i; } v; v.i = p << 16; return v.f;
}
__device__ __forceinline__ float phi(unsigned p) {
  union { float f; unsigned int i; } v; v.i = p & 0xffff0000u; return v.f;
}

// ---------------- dtype probe: are float arrays stored as f32 or bf16? ----------------
__global__ __launch_bounds__(256) void detect_k(const void* __restrict__ x, int* __restrict__ flag) {
  __shared__ int sc[256];
  const float* xf = (const float*)x;
  int t = threadIdx.x, c = 0;
  for (int i = 0; i < 4; ++i) {
    float a = fabsf(xf[t * 4 + i]);
    if (a > 1e-4f && a < 100.f) c++;  // NaN compares false
  }
  sc[t] = c;
  __syncthreads();
  for (int o = 128; o > 0; o >>= 1) { if (t < o) sc[t] += sc[t + o]; __syncthreads(); }
  if (t == 0) flag[0] = (sc[0] >= 512) ? 1 : 0;  // 1 = inputs are f32
}

// canonicalize x -> bf16
__global__ __launch_bounds__(256) void conv_x_k(const void* __restrict__ x, u16* __restrict__ xc,
                                                const int* __restrict__ flag) {
  int i = (blockIdx.x * 256 + threadIdx.x) * 4;
  if (i >= NN * 128) return;
  if (flag[0]) {
    const float* s = (const float*)x + i;
    xc[i] = f2bf(s[0]); xc[i + 1] = f2bf(s[1]); xc[i + 2] = f2bf(s[2]); xc[i + 3] = f2bf(s[3]);
  } else {
    *(uint2*)(xc + i) = *(const uint2*)((const u16*)x + i);
  }
}

// canonicalize W0..2 -> bf16 (3 x 16384)
__global__ __launch_bounds__(256) void conv_w_k(const void* __restrict__ w0, const void* __restrict__ w1,
                                                const void* __restrict__ w2, u16* __restrict__ wc,
                                                const int* __restrict__ flag) {
  int idx = blockIdx.x * 256 + threadIdx.x;
  const void* s = (idx >> 14) == 0 ? w0 : ((idx >> 14) == 1 ? w1 : w2);
  int l = idx & 16383;
  wc[idx] = flag[0] ? f2bf(((const float*)s)[l]) : ((const u16*)s)[l];
}

// canonicalize small params -> f32 block
// pf layout: l*384 + {a_src:0, a_dst:128, b:256}; lin_w at 1152 (1280); lin_b at 2432 (10)
__global__ __launch_bounds__(256) void conv_p_k(const void* as0, const void* ad0, const void* b0,
                                                const void* as1, const void* ad1, const void* b1,
                                                const void* as2, const void* ad2, const void* b2,
                                                const void* lw, const void* lb,
                                                float* __restrict__ pf, const int* __restrict__ flag) {
  const void* srcs[11] = {as0, ad0, b0, as1, ad1, b1, as2, ad2, b2, lw, lb};
  const int offs[12] = {0, 128, 256, 384, 512, 640, 768, 896, 1024, 1152, 2432, 2442};
  int f = flag[0];
  for (int idx = threadIdx.x; idx < 2442; idx += 256) {
    int k = 0;
    while (idx >= offs[k + 1]) k++;
    int l = idx - offs[k];
    pf[idx] = f ? ((const float*)srcs[k])[l] : bf2f(((const u16*)srcs[k])[l]);
  }
}

// ---------------- CSR build ----------------
__global__ __launch_bounds__(256) void init_k(int* counts, int* fill, int* roff, float* psum) {
  int i = blockIdx.x * 256 + threadIdx.x;
  if (i < NN) { counts[i] = 1; fill[i] = 0; }  // 1 = self loop
  if (i < NGRAPH * 128) psum[i] = 0.f;
  if (i == 0) roff[NN] = ET;
}

__global__ __launch_bounds__(256) void count_k(const int* __restrict__ ei, int* __restrict__ counts) {
  int e = blockIdx.x * 256 + threadIdx.x;
  if (e < EE) atomicAdd(&counts[ei[EE + e]], 1);
}

__global__ __launch_bounds__(256) void scan_a(const int* __restrict__ counts, int* __restrict__ part) {
  __shared__ int s[256];
  int t = threadIdx.x, i = blockIdx.x * 256 + t;
  s[t] = (i < NN) ? counts[i] : 0;
  __syncthreads();
  for (int o = 128; o > 0; o >>= 1) { if (t < o) s[t] += s[t + o]; __syncthreads(); }
  if (t == 0) part[blockIdx.x] = s[0];
}

__global__ __launch_bounds__(256) void scan_b(int* part) {  // 196 partials
  __shared__ int s[256];
  int t = threadIdx.x;
  int v = (t < 196) ? part[t] : 0;
  s[t] = v;
  __syncthreads();
  for (int o = 1; o < 256; o <<= 1) {
    int add = (t >= o) ? s[t - o] : 0;
    __syncthreads();
    s[t] += add;
    __syncthreads();
  }
  if (t < 196) part[t] = s[t] - v;  // exclusive
}

__global__ __launch_bounds__(256) void scan_c(const int* __restrict__ counts, const int* __restrict__ part,
                                              int* __restrict__ roff) {
  __shared__ int s[256];
  int t = threadIdx.x, i = blockIdx.x * 256 + t;
  int v = (i < NN) ? counts[i] : 0;
  s[t] = v;
  __syncthreads();
  for (int o = 1; o < 256; o <<= 1) {
    int add = (t >= o) ? s[t - o] : 0;
    __syncthreads();
    s[t] += add;
    __syncthreads();
  }
  if (i < NN) roff[i] = part[blockIdx.x] + s[t] - v;
}

__global__ __launch_bounds__(256) void fill_k(const int* __restrict__ ei, const int* __restrict__ roff,
                                              int* __restrict__ fill, int* __restrict__ csr) {
  int i = blockIdx.x * 256 + threadIdx.x;
  if (i >= ET) return;
  int s, d;
  if (i < EE) { s = ei[i]; d = ei[EE + i]; } else { s = d = i - EE; }
  int pos = roff[d] + atomicAdd(&fill[d], 1);
  if ((unsigned)pos < (unsigned)ET) csr[pos] = s;
}

// ---------------- GEMM + fused alpha: h2(packed bf16) = A @ W; al_s/al_d dots ----------------
__global__ __launch_bounds__(256) void gemm_k(const u16* __restrict__ A, const u16* __restrict__ Wg,
                                              const float* __restrict__ a_src, const float* __restrict__ a_dst,
                                              unsigned* __restrict__ h2, float* __restrict__ al_s,
                                              float* __restrict__ al_d) {
  __shared__ u16 lds[128 * 128];  // W, XOR-swizzled 16B granules
  int tid = threadIdx.x;
  for (int idx = tid; idx < 128 * 128; idx += 256) {
    int k = idx >> 7, c = idx & 127;
    int slot = (k >> 3) ^ (c & 15);
    lds[c * 128 + slot * 8 + (k & 7)] = Wg[idx];
  }
  __syncthreads();
  int wid = tid >> 6, lane = tid & 63;
  int l15 = lane & 15, quad = lane >> 4;
  int row0 = blockIdx.x * 64 + wid * 16;
  f32x4 acc[8];
#pragma unroll
  for (int t = 0; t < 8; ++t) { acc[t][0] = 0.f; acc[t][1] = 0.f; acc[t][2] = 0.f; acc[t][3] = 0.f; }
  int arow = row0 + l15;
  if (arow >= NN) arow = NN - 1;  // clamp: pad-row outputs never stored
#pragma unroll
  for (int ks = 0; ks < 4; ++ks) {
    short8 a = *(const short8*)(A + (size_t)arow * 128 + ks * 32 + quad * 8);
#pragma unroll
    for (int t = 0; t < 8; ++t) {
      int col = t * 16 + l15;
      int slot = (ks * 4 + quad) ^ l15;
      short8 b = *(const short8*)(&lds[col * 128 + slot * 8]);
      acc[t] = __builtin_amdgcn_mfma_f32_16x16x32_bf16(a, b, acc[t], 0, 0, 0);
    }
  }
  // preload attention vectors for this lane's columns
  float vs[8], vd[8];
#pragma unroll
  for (int t = 0; t < 8; ++t) { vs[t] = a_src[t * 16 + l15]; vd[t] = a_dst[t * 16 + l15]; }
  // epilogue: packed h2 write + per-row alpha dots
#pragma unroll
  for (int r = 0; r < 4; ++r) {
    int row = row0 + quad * 4 + r;
    // pack channels (c, c+64) into one dword: t in 0..3 pairs with t+4
#pragma unroll
    for (int t = 0; t < 4; ++t) {
      if (row < NN) {
        unsigned lo = f2bf(acc[t][r]);
        unsigned hiv = f2bf(acc[t + 4][r]);
        h2[(size_t)row * 64 + t * 16 + l15] = lo | (hiv << 16);
      }
    }
    // alpha dots per head: head0 = t 0..3, head1 = t 4..7
    float s0 = 0.f, s1 = 0.f, d0 = 0.f, d1 = 0.f;
#pragma unroll
    for (int t = 0; t < 4; ++t) { s0 += acc[t][r] * vs[t]; d0 += acc[t][r] * vd[t]; }
#pragma unroll
    for (int t = 4; t < 8; ++t) { s1 += acc[t][r] * vs[t]; d1 += acc[t][r] * vd[t]; }
#pragma unroll
    for (int o = 1; o < 16; o <<= 1) {
      s0 += __shfl_xor(s0, o); s1 += __shfl_xor(s1, o);
      d0 += __shfl_xor(d0, o); d1 += __shfl_xor(d1, o);
    }
    if (row < NN && l15 == 0) {
      al_s[2 * row] = s0; al_s[2 * row + 1] = s1;
      al_d[2 * row] = d0; al_d[2 * row + 1] = d1;
    }
  }
}

// ---------------- segment softmax + aggregation (one wave per dst node) ----------------
__global__ __launch_bounds__(256) void agg_k(const unsigned* __restrict__ h2, const float* __restrict__ al_s,
                                             const float* __restrict__ al_d, const int* __restrict__ roff,
                                             const int* __restrict__ csr, const float* __restrict__ bias,
                                             u16* __restrict__ oB, float* __restrict__ psum,
                                             const int* __restrict__ batch, int last) {
  int wid = threadIdx.x >> 6, lane = threadIdx.x & 63;
  int n = blockIdx.x * 4 + wid;
  if (n >= NN) return;
  int base = roff[n], deg = roff[n + 1] - base;
  float ad0 = al_d[2 * n], ad1 = al_d[2 * n + 1];
  float acc0 = 0.f, acc1 = 0.f, den0, den1;

  if (deg <= 64) {  // fast path (covers ~all nodes): one chunk, e cached in registers
    int sv = 0;
    float e0 = -1e30f, e1 = -1e30f;
    if (lane < deg) {
      sv = csr[base + lane];
      float as0 = al_s[2 * sv], as1 = al_s[2 * sv + 1];
      e0 = lrelu(as0 + ad0); e1 = lrelu(as1 + ad1);
    }
    float m0 = e0, m1 = e1;
#pragma unroll
    for (int o = 32; o > 0; o >>= 1) { m0 = fmaxf(m0, __shfl_xor(m0, o)); m1 = fmaxf(m1, __shfl_xor(m1, o)); }
    float w0 = (lane < deg) ? __expf(e0 - m0) : 0.f;
    float w1 = (lane < deg) ? __expf(e1 - m1) : 0.f;
    den0 = w0; den1 = w1;
#pragma unroll
    for (int o = 32; o > 0; o >>= 1) { den0 += __shfl_xor(den0, o); den1 += __shfl_xor(den1, o); }
    int j = 0;
    for (; j + 4 <= deg; j += 4) {  // 4 loads in flight -> hide gather latency
      int s0 = __shfl(sv, j), s1 = __shfl(sv, j + 1), s2 = __shfl(sv, j + 2), s3 = __shfl(sv, j + 3);
      unsigned p0 = h2[(size_t)s0 * 64 + lane];
      unsigned p1 = h2[(size_t)s1 * 64 + lane];
      unsigned p2 = h2[(size_t)s2 * 64 + lane];
      unsigned p3 = h2[(size_t)s3 * 64 + lane];
      float a0 = __shfl(w0, j), a1 = __shfl(w0, j + 1), a2 = __shfl(w0, j + 2), a3 = __shfl(w0, j + 3);
      float b0 = __shfl(w1, j), b1 = __shfl(w1, j + 1), b2 = __shfl(w1, j + 2), b3 = __shfl(w1, j + 3);
      acc0 += a0 * plo(p0); acc1 += b0 * phi(p0);
      acc0 += a1 * plo(p1); acc1 += b1 * phi(p1);
      acc0 += a2 * plo(p2); acc1 += b2 * phi(p2);
      acc0 += a3 * plo(p3); acc1 += b3 * phi(p3);
    }
    for (; j < deg; ++j) {
      int sj = __shfl(sv, j);
      unsigned p = h2[(size_t)sj * 64 + lane];
      acc0 += __shfl(w0, j) * plo(p);
      acc1 += __shfl(w1, j) * phi(p);
    }
  } else {  // generic chunked path (astronomically rare at mean deg 13)
    float m0 = -1e30f, m1 = -1e30f;
    for (int i = lane; i < deg; i += 64) {
      int s = csr[base + i];
      m0 = fmaxf(m0, lrelu(al_s[2 * s] + ad0));
      m1 = fmaxf(m1, lrelu(al_s[2 * s + 1] + ad1));
    }
#pragma unroll
    for (int o = 32; o > 0; o >>= 1) { m0 = fmaxf(m0, __shfl_xor(m0, o)); m1 = fmaxf(m1, __shfl_xor(m1, o)); }
    den0 = 0.f; den1 = 0.f;
    for (int c0 = 0; c0 < deg; c0 += 64) {
      int cnt = min(64, deg - c0);
      int sv = 0; float w0 = 0.f, w1 = 0.f;
      if (lane < cnt) {
        sv = csr[base + c0 + lane];
        w0 = __expf(lrelu(al_s[2 * sv] + ad0) - m0);
        w1 = __expf(lrelu(al_s[2 * sv + 1] + ad1) - m1);
      }
      for (int j = 0; j < cnt; ++j) {
        int sj = __shfl(sv, j);
        unsigned p = h2[(size_t)sj * 64 + lane];
        float w0j = __shfl(w0, j), w1j = __shfl(w1, j);
        acc0 += w0j * plo(p); acc1 += w1j * phi(p);
        den0 += w0j; den1 += w1j;
      }
    }
  }

  float v0 = acc0 / (den0 + 1e-16f) + bias[lane];
  float v1 = acc1 / (den1 + 1e-16f) + bias[64 + lane];
  if (last) {  // fused mean-pool numerator
    int g = batch[n]; if ((unsigned)g >= (unsigned)NGRAPH) g = 0;
    atomicAdd(&psum[g * 128 + lane], v0);
    atomicAdd(&psum[g * 128 + 64 + lane], v1);
  } else {  // ELU, store bf16 for next layer's MFMA
    v0 = v0 > 0.f ? v0 : __expf(v0) - 1.f;
    v1 = v1 > 0.f ? v1 : __expf(v1) - 1.f;
    oB[(size_t)n * 128 + lane] = f2bf(v0);
    oB[(size_t)n * 128 + 64 + lane] = f2bf(v1);
  }
}

// ---------------- final: mean + linear + softmax (f32 output!) ----------------
__device__ __forceinline__ int lbound(const int* a, int n, int v) {
  int lo = 0, hi = n;
  while (lo < hi) { int mid = (lo + hi) >> 1; if (a[mid] < v) lo = mid + 1; else hi = mid; }
  return lo;
}

__global__ __launch_bounds__(128) void final_k(const float* __restrict__ psum, const int* __restrict__ batch,
                                               const float* __restrict__ lw, const float* __restrict__ lb,
                                               float* __restrict__ out) {
  __shared__ float p[128];
  __shared__ float lg[NCLASS];
  int g = blockIdx.x, t = threadIdx.x;
  int cnt = lbound(batch, NN, g + 1) - lbound(batch, NN, g);
  p[t] = psum[g * 128 + t] / fmaxf((float)cnt, 1.f);
  __syncthreads();
  if (t < NCLASS) {
    float acc = lb[t];
    for (int c = 0; c < 128; ++c) acc += p[c] * lw[c * NCLASS + t];
    lg[t] = acc;
  }
  __syncthreads();
  if (t < NCLASS) {
    float m = -1e30f;
    for (int j = 0; j < NCLASS; ++j) m = fmaxf(m, lg[j]);
    float sum = 0.f;
    for (int j = 0; j < NCLASS; ++j) sum += __expf(lg[j] - m);
    out[g * NCLASS + t] = __expf(lg[t] - m) / sum;  // f32 store — d_out is float32
  }
}

extern "C" void kernel_launch(void* const* d_in, const int* in_sizes, int n_in,
                              void* d_out, int out_size, void* d_ws, size_t ws_size,
                              hipStream_t stream) {
  const void* x = d_in[0];
  const int* ei = (const int*)d_in[1];
  const int* batch = (const int*)d_in[2];
  float* out = (float*)d_out;

  size_t off = 0;
  auto alloc = [&](size_t bytes) -> void* {
    void* p = (char*)d_ws + off;
    off += (bytes + 255) & ~(size_t)255;
    return p;
  };
  int* flag = (int*)alloc(256);
  u16* xc = (u16*)alloc((size_t)NN * 128 * 2);
  u16* wc = (u16*)alloc((size_t)3 * 16384 * 2);
  float* pf = (float*)alloc(2442 * 4);
  unsigned* h2 = (unsigned*)alloc((size_t)NN * 64 * 4);  // packed bf16x2 (c, c+64)
  u16* xb = (u16*)alloc((size_t)NN * 128 * 2);
  float* al_s = (float*)alloc((size_t)NN * 2 * 4);
  float* al_d = (float*)alloc((size_t)NN * 2 * 4);
  int* counts = (int*)alloc((size_t)NN * 4);
  int* fillc = (int*)alloc((size_t)NN * 4);
  int* roff = (int*)alloc((size_t)(NN + 1) * 4);
  int* csr = (int*)alloc((size_t)ET * 4);
  int* part = (int*)alloc(256 * 4);
  float* psum = (float*)alloc((size_t)NGRAPH * 128 * 4);
  // total ~42 MB

  detect_k<<<1, 256, 0, stream>>>(x, flag);
  conv_x_k<<<6250, 256, 0, stream>>>(x, xc, flag);
  conv_w_k<<<192, 256, 0, stream>>>(d_in[3], d_in[7], d_in[11], wc, flag);
  conv_p_k<<<1, 256, 0, stream>>>(d_in[4], d_in[5], d_in[6], d_in[8], d_in[9], d_in[10],
                                  d_in[12], d_in[13], d_in[14], d_in[15], d_in[16], pf, flag);

  init_k<<<196, 256, 0, stream>>>(counts, fillc, roff, psum);
  count_k<<<2344, 256, 0, stream>>>(ei, counts);
  scan_a<<<196, 256, 0, stream>>>(counts, part);
  scan_b<<<1, 256, 0, stream>>>(part);
  scan_c<<<196, 256, 0, stream>>>(counts, part, roff);
  fill_k<<<2540, 256, 0, stream>>>(ei, roff, fillc, csr);

  const u16* Ain = xc;
  for (int l = 0; l < 3; ++l) {
    gemm_k<<<782, 256, 0, stream>>>(Ain, wc + l * 16384, pf + l * 384, pf + l * 384 + 128,
                                    h2, al_s, al_d);
    agg_k<<<12500, 256, 0, stream>>>(h2, al_s, al_d, roff, csr, pf + l * 384 + 256,
                                     xb, psum, batch, l == 2);
    Ain = xb;
  }
  final_k<<<NGRAPH, 128, 0, stream>>>(psum, batch, pf + 1152, pf + 2432, out);
}